// Round 4
// baseline (779.025 us; speedup 1.0000x reference)
//
#include <hip/hip_runtime.h>
#include <math.h>

#define B_  1024
#define S_  256
#define H_  512
#define E_  64
#define R_  32
#define L_  9
#define EPS_ 1e-6f
#define TB  8    // b-tile for MLP kernel

// ---------------------------------------------------------------------------
// Kernel 1: fused 2-layer MLP for the 4 live modules (m=0 -> e[0], m=1..3 -> r[0..2])
// h = tanh(x @ W1 + b1); out = h @ W2 + b2
// grid (B/TB, 4), block 256
// Layer-1: s-chunks of 4 -> 8 independent global loads + 8 ds_read_b128 per 64 FMAs.
// Layer-2: 4 independent accumulators (breaks the 512-long dependent FMA chain).
// ---------------------------------------------------------------------------
__global__ __launch_bounds__(256) void mlp_kernel(
    const float* __restrict__ x,     // [B,S]
    const float* __restrict__ eW1, const float* __restrict__ eb1,
    const float* __restrict__ eW2, const float* __restrict__ eb2,
    const float* __restrict__ rW1, const float* __restrict__ rb1,
    const float* __restrict__ rW2, const float* __restrict__ rb2,
    float* __restrict__ e0_out,      // [B,E]
    float* __restrict__ r_out)       // [3,B,R]
{
    __shared__ __align__(16) float xs[TB][S_];   // 8 KB
    __shared__ __align__(16) float hs[TB][H_];   // 16 KB
    const int t  = threadIdx.x;
    const int b0 = blockIdx.x * TB;
    const int m  = blockIdx.y;       // 0 = e0, 1..3 = r0..r2

    // float4 staging of the x tile: TB*S_/4 = 512 float4, 2 per thread
    {
        const float4* x4 = (const float4*)(x + (size_t)b0 * S_);
        float4* xs4 = (float4*)&xs[0][0];
        xs4[t]       = x4[t];
        xs4[t + 256] = x4[t + 256];
    }
    __syncthreads();

    const float* W1 = (m == 0) ? eW1 : (rW1 + (size_t)(m - 1) * S_ * H_);
    const float* b1 = (m == 0) ? eb1 : (rb1 + (size_t)(m - 1) * H_);

    float acc0[TB], acc1[TB];
    #pragma unroll
    for (int bb = 0; bb < TB; ++bb) { acc0[bb] = 0.0f; acc1[bb] = 0.0f; }

    for (int s4 = 0; s4 < S_ / 4; ++s4) {
        const float* Wp = W1 + (size_t)(4 * s4) * H_ + t;
        // 8 independent global loads (L2-resident after first pass)
        float wa0 = Wp[0];          float wb0 = Wp[256];
        float wa1 = Wp[H_];         float wb1 = Wp[H_ + 256];
        float wa2 = Wp[2 * H_];     float wb2 = Wp[2 * H_ + 256];
        float wa3 = Wp[3 * H_];     float wb3 = Wp[3 * H_ + 256];
        #pragma unroll
        for (int bb = 0; bb < TB; ++bb) {
            float4 xv = ((const float4*)&xs[bb][0])[s4];   // ds_read_b128
            acc0[bb] = fmaf(xv.x, wa0, acc0[bb]);
            acc1[bb] = fmaf(xv.x, wb0, acc1[bb]);
            acc0[bb] = fmaf(xv.y, wa1, acc0[bb]);
            acc1[bb] = fmaf(xv.y, wb1, acc1[bb]);
            acc0[bb] = fmaf(xv.z, wa2, acc0[bb]);
            acc1[bb] = fmaf(xv.z, wb2, acc1[bb]);
            acc0[bb] = fmaf(xv.w, wa3, acc0[bb]);
            acc1[bb] = fmaf(xv.w, wb3, acc1[bb]);
        }
    }
    float bias0 = b1[t], bias1 = b1[t + 256];
    #pragma unroll
    for (int bb = 0; bb < TB; ++bb) {
        hs[bb][t]       = tanhf(acc0[bb] + bias0);
        hs[bb][t + 256] = tanhf(acc1[bb] + bias1);
    }
    __syncthreads();

    if (m == 0) {
        const float* W2 = eW2;
        const float* b2 = eb2;
        int o  = t & 63;
        int bq = t >> 6;                     // 0..3
        #pragma unroll
        for (int i = 0; i < TB / 4; ++i) {
            int bb = bq + i * 4;
            float a0 = 0.f, a1 = 0.f, a2 = 0.f, a3 = 0.f;
            #pragma unroll 4
            for (int j = 0; j < H_; j += 4) {
                float4 hv = ((const float4*)&hs[bb][0])[j >> 2];  // broadcast b128
                a0 = fmaf(hv.x, W2[(size_t)(j + 0) * E_ + o], a0);
                a1 = fmaf(hv.y, W2[(size_t)(j + 1) * E_ + o], a1);
                a2 = fmaf(hv.z, W2[(size_t)(j + 2) * E_ + o], a2);
                a3 = fmaf(hv.w, W2[(size_t)(j + 3) * E_ + o], a3);
            }
            e0_out[(size_t)(b0 + bb) * E_ + o] = b2[o] + ((a0 + a1) + (a2 + a3));
        }
    } else {
        const float* W2 = rW2 + (size_t)(m - 1) * H_ * R_;
        const float* b2 = rb2 + (size_t)(m - 1) * R_;
        int o  = t & 31;
        int bb = t >> 5;                     // 0..7 == TB
        float a0 = 0.f, a1 = 0.f, a2 = 0.f, a3 = 0.f;
        #pragma unroll 4
        for (int j = 0; j < H_; j += 4) {
            float4 hv = ((const float4*)&hs[bb][0])[j >> 2];
            a0 = fmaf(hv.x, W2[(size_t)(j + 0) * R_ + o], a0);
            a1 = fmaf(hv.y, W2[(size_t)(j + 1) * R_ + o], a1);
            a2 = fmaf(hv.z, W2[(size_t)(j + 2) * R_ + o], a2);
            a3 = fmaf(hv.w, W2[(size_t)(j + 3) * R_ + o], a3);
        }
        r_out[((size_t)(m - 1) * B_ + (b0 + bb)) * R_ + o] = b2[o] + ((a0 + a1) + (a2 + a3));
    }
}

// ---------------------------------------------------------------------------
// Kernel 2: fused per-b TPR chain, single pass over tpr[b].
//  Phase M: stream tpr[b] (512 KB) once (regular cached float4 loads —
//    nt hint removed: read-once data, L2 pollution irrelevant, and the
//    6.3 TB/s ceiling was measured with cached loads):
//    - t0 partial[f] += e0[e] * (sum_r r0[r]*tpr[b,e,r,f])   (regs -> red)
//    - M1[e][f], M2[e][f] into LDS (32 KB)
//    r-outer / e-inner: weight triple read once per r (96 ds_reads vs 384),
//    16 independent global loads in flight per unrolled iteration.
//  Phase S: wave 0 only (no barriers inside): LN chain + Z projection.
//  No waves/EU floor: latency hiding needs only ~1 block/CU (64 KB in
//  flight/block vs 9 KB needed at 900cy); don't cap the allocator.
// ---------------------------------------------------------------------------
__global__ __launch_bounds__(256) void tpr_kernel(
    const float* __restrict__ tpr,   // [B,E,R,E]
    const float* __restrict__ e0,    // [B,E]
    const float* __restrict__ rws,   // [3,B,R]
    const float* __restrict__ ln_g,  // [3,E]
    const float* __restrict__ ln_b,  // [3,E]
    const float* __restrict__ Z,     // [E,L]
    float* __restrict__ out)         // [B,L]
{
    __shared__ __align__(16) float M[2][E_][E_];     // 32 KB  (M1, M2)
    __shared__ __align__(16) float red[16][E_];      // 4 KB   (t0 partials)
    __shared__ float xcur[E_];
    __shared__ float ssum_sh[E_];
    __shared__ float rsh[3][R_];
    __shared__ float e0sh[E_];

    const int t = threadIdx.x;
    const int b = blockIdx.x;

    if (t < 96) { int k = t >> 5, j = t & 31; rsh[k][j] = rws[((size_t)k * B_ + b) * R_ + j]; }
    if (t < E_) e0sh[t] = e0[(size_t)b * E_ + t];
    __syncthreads();

    // ---- Phase M: stream tpr[b] once ----
    const float4* tpr4 = (const float4*)(tpr + (size_t)b * E_ * R_ * E_);
    const int f4 = t & 15;       // float4 index within the 64-float f row
    const int eg = t >> 4;       // 0..15; this thread owns e = eg + 16*ep, ep=0..3

    float4 a0[4], a1[4], a2[4];
    #pragma unroll
    for (int ep = 0; ep < 4; ++ep) {
        a0[ep] = (float4){0, 0, 0, 0};
        a1[ep] = (float4){0, 0, 0, 0};
        a2[ep] = (float4){0, 0, 0, 0};
    }

    #pragma unroll 4
    for (int r = 0; r < R_; ++r) {
        float w0 = rsh[0][r], w1 = rsh[1][r], w2 = rsh[2][r];
        #pragma unroll
        for (int ep = 0; ep < 4; ++ep) {
            float4 v = tpr4[(eg + 16 * ep) * 512 + r * 16 + f4];
            a0[ep].x = fmaf(w0, v.x, a0[ep].x); a0[ep].y = fmaf(w0, v.y, a0[ep].y);
            a0[ep].z = fmaf(w0, v.z, a0[ep].z); a0[ep].w = fmaf(w0, v.w, a0[ep].w);
            a1[ep].x = fmaf(w1, v.x, a1[ep].x); a1[ep].y = fmaf(w1, v.y, a1[ep].y);
            a1[ep].z = fmaf(w1, v.z, a1[ep].z); a1[ep].w = fmaf(w1, v.w, a1[ep].w);
            a2[ep].x = fmaf(w2, v.x, a2[ep].x); a2[ep].y = fmaf(w2, v.y, a2[ep].y);
            a2[ep].z = fmaf(w2, v.z, a2[ep].z); a2[ep].w = fmaf(w2, v.w, a2[ep].w);
        }
    }

    float4 t0p = {0, 0, 0, 0};
    #pragma unroll
    for (int ep = 0; ep < 4; ++ep) {
        int e = eg + 16 * ep;
        ((float4*)&M[0][e][0])[f4] = a1[ep];
        ((float4*)&M[1][e][0])[f4] = a2[ep];
        float ev = e0sh[e];
        t0p.x = fmaf(ev, a0[ep].x, t0p.x); t0p.y = fmaf(ev, a0[ep].y, t0p.y);
        t0p.z = fmaf(ev, a0[ep].z, t0p.z); t0p.w = fmaf(ev, a0[ep].w, t0p.w);
    }
    ((float4*)&red[eg][0])[f4] = t0p;
    __syncthreads();

    // ---- Phase S: wave 0 only, no barriers (in-wave LDS ordering suffices) ----
    if (t < E_) {
        const int f = t;
        float acc = 0.0f;
        #pragma unroll
        for (int g = 0; g < 16; ++g) acc += red[g][f];

        float ssum = 0.0f;
        #pragma unroll
        for (int k = 0; k < 3; ++k) {
            float s = acc;
            #pragma unroll
            for (int off = 32; off >= 1; off >>= 1) s += __shfl_xor(s, off, 64);
            float mu = s * (1.0f / 64.0f);
            float d = acc - mu;
            float vs = d * d;
            #pragma unroll
            for (int off = 32; off >= 1; off >>= 1) vs += __shfl_xor(vs, off, 64);
            float var = vs * (1.0f / 64.0f);
            float iv = ln_g[k * E_ + f] * d * rsqrtf(var + EPS_) + ln_b[k * E_ + f];
            ssum += iv;
            if (k < 2) {
                xcur[f] = iv;
                // 4 independent partials: breaks the 64-deep dependent FMA chain
                float n0 = 0.f, n1 = 0.f, n2 = 0.f, n3 = 0.f;
                #pragma unroll 4
                for (int e = 0; e < E_; e += 4) {
                    n0 = fmaf(xcur[e + 0], M[k][e + 0][f], n0);
                    n1 = fmaf(xcur[e + 1], M[k][e + 1][f], n1);
                    n2 = fmaf(xcur[e + 2], M[k][e + 2][f], n2);
                    n3 = fmaf(xcur[e + 3], M[k][e + 3][f], n3);
                }
                acc = (n0 + n1) + (n2 + n3);
            }
        }
        ssum_sh[f] = ssum;

        if (t < L_) {
            float o = 0.0f;
            #pragma unroll
            for (int f2 = 0; f2 < E_; ++f2)
                o = fmaf(ssum_sh[f2], Z[f2 * L_ + t], o);
            out[(size_t)b * L_ + t] = o;
        }
    }
}

// ---------------------------------------------------------------------------
extern "C" void kernel_launch(void* const* d_in, const int* in_sizes, int n_in,
                              void* d_out, int out_size, void* d_ws, size_t ws_size,
                              hipStream_t stream) {
    const float* x    = (const float*)d_in[0];
    const float* tpr  = (const float*)d_in[1];
    const float* eW1  = (const float*)d_in[2];
    const float* eb1  = (const float*)d_in[3];
    const float* eW2  = (const float*)d_in[4];
    const float* eb2  = (const float*)d_in[5];
    const float* rW1  = (const float*)d_in[6];
    const float* rb1  = (const float*)d_in[7];
    const float* rW2  = (const float*)d_in[8];
    const float* rb2  = (const float*)d_in[9];
    const float* ln_g = (const float*)d_in[10];
    const float* ln_b = (const float*)d_in[11];
    const float* Z    = (const float*)d_in[12];
    float* out = (float*)d_out;

    float* e0_ws = (float*)d_ws;             // B*E floats
    float* r_ws  = e0_ws + (size_t)B_ * E_;  // 3*B*R floats

    dim3 g1(B_ / TB, 4);
    mlp_kernel<<<g1, 256, 0, stream>>>(x, eW1, eb1, eW2, eb2,
                                       rW1, rb1, rW2, rb2, e0_ws, r_ws);
    tpr_kernel<<<B_, 256, 0, stream>>>(tpr, e0_ws, r_ws, ln_g, ln_b, Z, out);
}

// Round 6
// 748.135 us; speedup vs baseline: 1.0413x; 1.0413x over previous
//
#include <hip/hip_runtime.h>
#include <math.h>

#define B_  1024
#define S_  256
#define H_  512
#define E_  64
#define R_  32
#define L_  9
#define EPS_ 1e-6f
#define TB  8    // b-tile for MLP kernel

// ---------------------------------------------------------------------------
// Kernel 1: fused 2-layer MLP for the 4 live modules (m=0 -> e[0], m=1..3 -> r[0..2])
// h = tanh(x @ W1 + b1); out = h @ W2 + b2
// grid (B/TB, 4), block 256
// ---------------------------------------------------------------------------
__global__ __launch_bounds__(256) void mlp_kernel(
    const float* __restrict__ x,     // [B,S]
    const float* __restrict__ eW1, const float* __restrict__ eb1,
    const float* __restrict__ eW2, const float* __restrict__ eb2,
    const float* __restrict__ rW1, const float* __restrict__ rb1,
    const float* __restrict__ rW2, const float* __restrict__ rb2,
    float* __restrict__ e0_out,      // [B,E]
    float* __restrict__ r_out)       // [3,B,R]
{
    __shared__ __align__(16) float xs[TB][S_];   // 8 KB
    __shared__ __align__(16) float hs[TB][H_];   // 16 KB
    const int t  = threadIdx.x;
    const int b0 = blockIdx.x * TB;
    const int m  = blockIdx.y;       // 0 = e0, 1..3 = r0..r2

    {
        const float4* x4 = (const float4*)(x + (size_t)b0 * S_);
        float4* xs4 = (float4*)&xs[0][0];
        xs4[t]       = x4[t];
        xs4[t + 256] = x4[t + 256];
    }
    __syncthreads();

    const float* W1 = (m == 0) ? eW1 : (rW1 + (size_t)(m - 1) * S_ * H_);
    const float* b1 = (m == 0) ? eb1 : (rb1 + (size_t)(m - 1) * H_);

    float acc0[TB], acc1[TB];
    #pragma unroll
    for (int bb = 0; bb < TB; ++bb) { acc0[bb] = 0.0f; acc1[bb] = 0.0f; }

    for (int s4 = 0; s4 < S_ / 4; ++s4) {
        const float* Wp = W1 + (size_t)(4 * s4) * H_ + t;
        float wa0 = Wp[0];          float wb0 = Wp[256];
        float wa1 = Wp[H_];         float wb1 = Wp[H_ + 256];
        float wa2 = Wp[2 * H_];     float wb2 = Wp[2 * H_ + 256];
        float wa3 = Wp[3 * H_];     float wb3 = Wp[3 * H_ + 256];
        #pragma unroll
        for (int bb = 0; bb < TB; ++bb) {
            float4 xv = ((const float4*)&xs[bb][0])[s4];   // ds_read_b128
            acc0[bb] = fmaf(xv.x, wa0, acc0[bb]);
            acc1[bb] = fmaf(xv.x, wb0, acc1[bb]);
            acc0[bb] = fmaf(xv.y, wa1, acc0[bb]);
            acc1[bb] = fmaf(xv.y, wb1, acc1[bb]);
            acc0[bb] = fmaf(xv.z, wa2, acc0[bb]);
            acc1[bb] = fmaf(xv.z, wb2, acc1[bb]);
            acc0[bb] = fmaf(xv.w, wa3, acc0[bb]);
            acc1[bb] = fmaf(xv.w, wb3, acc1[bb]);
        }
    }
    float bias0 = b1[t], bias1 = b1[t + 256];
    #pragma unroll
    for (int bb = 0; bb < TB; ++bb) {
        hs[bb][t]       = tanhf(acc0[bb] + bias0);
        hs[bb][t + 256] = tanhf(acc1[bb] + bias1);
    }
    __syncthreads();

    if (m == 0) {
        const float* W2 = eW2;
        const float* b2 = eb2;
        int o  = t & 63;
        int bq = t >> 6;                     // 0..3
        #pragma unroll
        for (int i = 0; i < TB / 4; ++i) {
            int bb = bq + i * 4;
            float a0 = 0.f, a1 = 0.f, a2 = 0.f, a3 = 0.f;
            #pragma unroll 4
            for (int j = 0; j < H_; j += 4) {
                float4 hv = ((const float4*)&hs[bb][0])[j >> 2];
                a0 = fmaf(hv.x, W2[(size_t)(j + 0) * E_ + o], a0);
                a1 = fmaf(hv.y, W2[(size_t)(j + 1) * E_ + o], a1);
                a2 = fmaf(hv.z, W2[(size_t)(j + 2) * E_ + o], a2);
                a3 = fmaf(hv.w, W2[(size_t)(j + 3) * E_ + o], a3);
            }
            e0_out[(size_t)(b0 + bb) * E_ + o] = b2[o] + ((a0 + a1) + (a2 + a3));
        }
    } else {
        const float* W2 = rW2 + (size_t)(m - 1) * H_ * R_;
        const float* b2 = rb2 + (size_t)(m - 1) * R_;
        int o  = t & 31;
        int bb = t >> 5;                     // 0..7 == TB
        float a0 = 0.f, a1 = 0.f, a2 = 0.f, a3 = 0.f;
        #pragma unroll 4
        for (int j = 0; j < H_; j += 4) {
            float4 hv = ((const float4*)&hs[bb][0])[j >> 2];
            a0 = fmaf(hv.x, W2[(size_t)(j + 0) * R_ + o], a0);
            a1 = fmaf(hv.y, W2[(size_t)(j + 1) * R_ + o], a1);
            a2 = fmaf(hv.z, W2[(size_t)(j + 2) * R_ + o], a2);
            a3 = fmaf(hv.w, W2[(size_t)(j + 3) * R_ + o], a3);
        }
        r_out[((size_t)(m - 1) * B_ + (b0 + bb)) * R_ + o] = b2[o] + ((a0 + a1) + (a2 + a3));
    }
}

// ---------------------------------------------------------------------------
// Kernel 2: fused per-b TPR chain, single pass over tpr[b].
//  Phase M: each wave owns a CONTIGUOUS 128 KB (16 e-rows);
//    every wave-load is a sequential, fully-coalesced 1 KB (the 6.3 TB/s
//    copy-kernel pattern). r-weights preloaded into 24 registers (zero LDS
//    reads in the stream). Per-e k-sums combined via 2 shfl_xor steps.
//    Unroll-8 => 8 independent loads in flight at ~85 live VGPRs (no spill,
//    4 blocks/CU).
//  Phase S: wave 0 only (no barriers inside): LN chain + Z projection.
// ---------------------------------------------------------------------------
__global__ __launch_bounds__(256) void tpr_kernel(
    const float* __restrict__ tpr,   // [B,E,R,E]
    const float* __restrict__ e0,    // [B,E]
    const float* __restrict__ rws,   // [3,B,R]
    const float* __restrict__ ln_g,  // [3,E]
    const float* __restrict__ ln_b,  // [3,E]
    const float* __restrict__ Z,     // [E,L]
    float* __restrict__ out)         // [B,L]
{
    __shared__ __align__(16) float M[2][E_][E_];     // 32 KB  (M1, M2)
    __shared__ __align__(16) float red[4][E_];       // 1 KB   (t0 partials, per wave)
    __shared__ float xcur[E_];
    __shared__ float ssum_sh[E_];
    __shared__ float rsh[3][R_];
    __shared__ float e0sh[E_];

    const int t = threadIdx.x;
    const int b = blockIdx.x;

    if (t < 96) { int k = t >> 5, j = t & 31; rsh[k][j] = rws[((size_t)k * B_ + b) * R_ + j]; }
    if (t < E_) e0sh[t] = e0[(size_t)b * E_ + t];
    __syncthreads();

    // ---- Phase M: contiguous per-wave stream ----
    const int w  = t >> 6;       // wave 0..3: owns e in [w*16, w*16+16)
    const int j  = t & 63;       // lane
    const int jh = j >> 4;       // r-subgroup 0..3
    const float4* base = (const float4*)(tpr + (size_t)b * E_ * R_ * E_) + w * 8192;

    // preload this lane's r-weights: r = it*4 + jh, it = 0..7
    float wk0[8], wk1[8], wk2[8];
    #pragma unroll
    for (int it = 0; it < 8; ++it) {
        int r = it * 4 + jh;
        wk0[it] = rsh[0][r]; wk1[it] = rsh[1][r]; wk2[it] = rsh[2][r];
    }

    float4 t0p = {0, 0, 0, 0};
    for (int el = 0; el < 16; ++el) {
        float4 a0 = {0,0,0,0}, a1 = {0,0,0,0}, a2 = {0,0,0,0};
        #pragma unroll
        for (int it = 0; it < 8; ++it) {
            float4 v = base[el * 512 + it * 64 + j];   // contiguous 1 KB per wave-load
            float w0 = wk0[it], w1 = wk1[it], w2 = wk2[it];
            a0.x = fmaf(w0, v.x, a0.x); a0.y = fmaf(w0, v.y, a0.y);
            a0.z = fmaf(w0, v.z, a0.z); a0.w = fmaf(w0, v.w, a0.w);
            a1.x = fmaf(w1, v.x, a1.x); a1.y = fmaf(w1, v.y, a1.y);
            a1.z = fmaf(w1, v.z, a1.z); a1.w = fmaf(w1, v.w, a1.w);
            a2.x = fmaf(w2, v.x, a2.x); a2.y = fmaf(w2, v.y, a2.y);
            a2.z = fmaf(w2, v.z, a2.z); a2.w = fmaf(w2, v.w, a2.w);
        }
        // reduce across the 4 r-subgroups (lanes ^16, ^32); f4 = j&15 preserved
        #pragma unroll
        for (int st = 16; st <= 32; st <<= 1) {
            a0.x += __shfl_xor(a0.x, st); a0.y += __shfl_xor(a0.y, st);
            a0.z += __shfl_xor(a0.z, st); a0.w += __shfl_xor(a0.w, st);
            a1.x += __shfl_xor(a1.x, st); a1.y += __shfl_xor(a1.y, st);
            a1.z += __shfl_xor(a1.z, st); a1.w += __shfl_xor(a1.w, st);
            a2.x += __shfl_xor(a2.x, st); a2.y += __shfl_xor(a2.y, st);
            a2.z += __shfl_xor(a2.z, st); a2.w += __shfl_xor(a2.w, st);
        }
        const int e = w * 16 + el;
        if (j < 16) {
            ((float4*)&M[0][e][0])[j] = a1;
            ((float4*)&M[1][e][0])[j] = a2;
        }
        float ev = e0sh[e];
        t0p.x = fmaf(ev, a0.x, t0p.x); t0p.y = fmaf(ev, a0.y, t0p.y);
        t0p.z = fmaf(ev, a0.z, t0p.z); t0p.w = fmaf(ev, a0.w, t0p.w);
    }
    if (j < 16) ((float4*)&red[w][0])[j] = t0p;
    __syncthreads();

    // ---- Phase S: wave 0 only, no barriers (in-wave LDS ordering suffices) ----
    if (t < E_) {
        const int f = t;
        float acc = 0.0f;
        #pragma unroll
        for (int g = 0; g < 4; ++g) acc += red[g][f];

        float ssum = 0.0f;
        #pragma unroll
        for (int k = 0; k < 3; ++k) {
            float s = acc;
            #pragma unroll
            for (int off = 32; off >= 1; off >>= 1) s += __shfl_xor(s, off, 64);
            float mu = s * (1.0f / 64.0f);
            float d = acc - mu;
            float vs = d * d;
            #pragma unroll
            for (int off = 32; off >= 1; off >>= 1) vs += __shfl_xor(vs, off, 64);
            float var = vs * (1.0f / 64.0f);
            float iv = ln_g[k * E_ + f] * d * rsqrtf(var + EPS_) + ln_b[k * E_ + f];
            ssum += iv;
            if (k < 2) {
                xcur[f] = iv;
                float n0 = 0.f, n1 = 0.f, n2 = 0.f, n3 = 0.f;
                #pragma unroll 4
                for (int e = 0; e < E_; e += 4) {
                    n0 = fmaf(xcur[e + 0], M[k][e + 0][f], n0);
                    n1 = fmaf(xcur[e + 1], M[k][e + 1][f], n1);
                    n2 = fmaf(xcur[e + 2], M[k][e + 2][f], n2);
                    n3 = fmaf(xcur[e + 3], M[k][e + 3][f], n3);
                }
                acc = (n0 + n1) + (n2 + n3);
            }
        }
        ssum_sh[f] = ssum;

        if (t < L_) {
            float o = 0.0f;
            #pragma unroll
            for (int f2 = 0; f2 < E_; ++f2)
                o = fmaf(ssum_sh[f2], Z[f2 * L_ + t], o);
            out[(size_t)b * L_ + t] = o;
        }
    }
}

// ---------------------------------------------------------------------------
extern "C" void kernel_launch(void* const* d_in, const int* in_sizes, int n_in,
                              void* d_out, int out_size, void* d_ws, size_t ws_size,
                              hipStream_t stream) {
    const float* x    = (const float*)d_in[0];
    const float* tpr  = (const float*)d_in[1];
    const float* eW1  = (const float*)d_in[2];
    const float* eb1  = (const float*)d_in[3];
    const float* eW2  = (const float*)d_in[4];
    const float* eb2  = (const float*)d_in[5];
    const float* rW1  = (const float*)d_in[6];
    const float* rb1  = (const float*)d_in[7];
    const float* rW2  = (const float*)d_in[8];
    const float* rb2  = (const float*)d_in[9];
    const float* ln_g = (const float*)d_in[10];
    const float* ln_b = (const float*)d_in[11];
    const float* Z    = (const float*)d_in[12];
    float* out = (float*)d_out;

    float* e0_ws = (float*)d_ws;             // B*E floats
    float* r_ws  = e0_ws + (size_t)B_ * E_;  // 3*B*R floats

    dim3 g1(B_ / TB, 4);
    mlp_kernel<<<g1, 256, 0, stream>>>(x, eW1, eb1, eW2, eb2,
                                       rW1, rb1, rW2, rb2, e0_ws, r_ws);
    tpr_kernel<<<B_, 256, 0, stream>>>(tpr, e0_ws, r_ws, ln_g, ln_b, Z, out);
}